// Round 3
// baseline (57.864 us; speedup 1.0000x reference)
//
#include <hip/hip_runtime.h>
#include <math.h>

// NEG_INF = -2^32+1 (rounds to -4294967296.0f in fp32, same as the reference's cast)
#define NEG_INF_F (-4294967295.0f)

typedef float f4 __attribute__((ext_vector_type(4)));  // native vec for nontemporal builtins

constexpr int B_ = 128;
constexpr int T_ = 8192;
constexpr int U_ = 64;
constexpr int NCHUNK = 16;           // T-chunks per batch
constexpr int CHUNK  = T_ / NCHUNK;  // 512 rows per block

// ---------------------------------------------------------------------------
// Fused kernel: each block (b, chunk) redundantly computes batch b's softmax
// stats from align/mask (128 KB, L2/L3-resident across the 16 replicas),
// stages its own 512-weight slice in LDS, then streams its 128 KB slab of
// value with nontemporal float4 loads, accumulating the weighted sum.
// Deterministic partials to ws; no atomics.
// ---------------------------------------------------------------------------
__global__ __launch_bounds__(256) void k_fused(const float* __restrict__ align,
                                               const int* __restrict__ mask,
                                               const float* __restrict__ value,
                                               float* __restrict__ partial) {
  const int b     = blockIdx.x / NCHUNK;
  const int chunk = blockIdx.x % NCHUNK;
  const int tid   = threadIdx.x;

  const float4* a4 = (const float4*)(align + (size_t)b * T_);
  const int4*   m4 = (const int4*)(mask + (size_t)b * T_);

  // ---- phase 1: masked scores in registers (32 per thread, coalesced) ----
  float sc[32];
#pragma unroll
  for (int j = 0; j < 8; ++j) {
    const float4 av = a4[j * 256 + tid];
    const int4   mv = m4[j * 256 + tid];
    sc[j * 4 + 0] = mv.x ? av.x : NEG_INF_F;
    sc[j * 4 + 1] = mv.y ? av.y : NEG_INF_F;
    sc[j * 4 + 2] = mv.z ? av.z : NEG_INF_F;
    sc[j * 4 + 3] = mv.w ? av.w : NEG_INF_F;
  }

  float lmax = sc[0];
#pragma unroll
  for (int i = 1; i < 32; ++i) lmax = fmaxf(lmax, sc[i]);
#pragma unroll
  for (int off = 32; off > 0; off >>= 1) lmax = fmaxf(lmax, __shfl_xor(lmax, off));

  __shared__ float red[4];
  __shared__ float s_m, s_invl;
  if ((tid & 63) == 0) red[tid >> 6] = lmax;
  __syncthreads();
  if (tid == 0) s_m = fmaxf(fmaxf(red[0], red[1]), fmaxf(red[2], red[3]));
  __syncthreads();
  const float m = s_m;

  float lsum = 0.f;
#pragma unroll
  for (int i = 0; i < 32; ++i) { sc[i] = __expf(sc[i] - m); lsum += sc[i]; }
#pragma unroll
  for (int off = 32; off > 0; off >>= 1) lsum += __shfl_xor(lsum, off);
  if ((tid & 63) == 0) red[tid >> 6] = lsum;
  __syncthreads();
  if (tid == 0) s_invl = 1.0f / (red[0] + red[1] + red[2] + red[3]);
  __syncthreads();
  const float invl = s_invl;

  // ---- stage this block's 512-weight slice into LDS ----
  // float4 index f = j*256 + tid; chunk covers f in [chunk*128, chunk*128+128)
  // -> owner threads: (tid>>7) == (chunk&1), j = chunk>>1, slot k = tid&127.
  __shared__ float w_s[CHUNK];
  if ((tid >> 7) == (chunk & 1)) {
    const int jown = chunk >> 1;
    const int k    = tid & 127;
    ((float4*)w_s)[k] = make_float4(sc[jown * 4 + 0] * invl, sc[jown * 4 + 1] * invl,
                                    sc[jown * 4 + 2] * invl, sc[jown * 4 + 3] * invl);
  }
  __syncthreads();

  // ---- phase 2: stream the 128 KB value slab (nontemporal, coalesced) ----
  const int grp  = tid >> 4;   // row within the 16-row slab
  const int lane = tid & 15;   // which float4 of the 64-float row
  const f4* v4 = (const f4*)(value + (size_t)b * T_ * U_) +
                 (size_t)chunk * CHUNK * 16;

  f4 acc = (f4)(0.f);
#pragma unroll 4
  for (int it = 0; it < CHUNK / 16; ++it) {
    const int tl = it * 16 + grp;
    const float wt = w_s[tl];
    const f4 v = __builtin_nontemporal_load(&v4[(size_t)tl * 16 + lane]);
    acc += wt * v;
  }

  // ---- phase 3: block reduction over the 16 row-groups ----
  __shared__ f4 lds[16][16];
  lds[grp][lane] = acc;
  __syncthreads();
#pragma unroll
  for (int s = 8; s > 0; s >>= 1) {
    if (grp < s) {
      acc += lds[grp + s][lane];
      lds[grp][lane] = acc;
    }
    __syncthreads();
  }
  if (grp == 0) {
    f4* p = (f4*)(partial + ((size_t)b * NCHUNK + chunk) * U_);
    p[lane] = acc;
  }
}

// ---------------------------------------------------------------------------
// Final reduction: NCHUNK partials per (b,u) -> out. 8192 outputs.
// ---------------------------------------------------------------------------
__global__ __launch_bounds__(256) void k_final(const float* __restrict__ partial,
                                               float* __restrict__ out) {
  const int idx = blockIdx.x * blockDim.x + threadIdx.x;  // 0 .. B*U-1
  const int b = idx / U_;
  const int u = idx % U_;
  const float* p = partial + (size_t)b * NCHUNK * U_ + u;
  float s = 0.f;
#pragma unroll
  for (int c = 0; c < NCHUNK; ++c) s += p[c * U_];
  out[idx] = s;
}

extern "C" void kernel_launch(void* const* d_in, const int* in_sizes, int n_in,
                              void* d_out, int out_size, void* d_ws, size_t ws_size,
                              hipStream_t stream) {
  const float* align = (const float*)d_in[0];
  const float* value = (const float*)d_in[1];
  const int*   mask  = (const int*)d_in[2];
  float* out = (float*)d_out;

  float* partial = (float*)d_ws;  // B*NCHUNK*U floats = 512 KiB

  k_fused<<<B_ * NCHUNK, 256, 0, stream>>>(align, mask, value, partial);
  k_final<<<(B_ * U_) / 256, 256, 0, stream>>>(partial, out);
}

// Round 4
// 53.544 us; speedup vs baseline: 1.0807x; 1.0807x over previous
//
#include <hip/hip_runtime.h>
#include <math.h>

// NEG_INF = -2^32+1 (rounds to -4294967296.0f in fp32, same as the reference's cast)
#define NEG_INF_F (-4294967295.0f)

typedef float f4 __attribute__((ext_vector_type(4)));

constexpr int B_ = 128;
constexpr int T_ = 8192;
constexpr int U_ = 64;
constexpr int NSTAT  = 8;            // stat-blocks per batch (1024 elems each)
constexpr int NCHUNK = 16;           // stream-chunks per batch
constexpr int CHUNK  = T_ / NCHUNK;  // 512 rows per stream block

// ---------------------------------------------------------------------------
// Kernel 1: online-softmax partial stats. 8 blocks per batch, each reduces a
// 1024-slice of masked scores to (m_i, l_i) where l_i = sum exp(x - m_i).
// 1024 blocks x 256 threads, 4 elems/thread, fully coalesced.
// ---------------------------------------------------------------------------
__global__ __launch_bounds__(256) void k_stats(const float* __restrict__ align,
                                               const int* __restrict__ mask,
                                               float2* __restrict__ stats) {
  const int b   = blockIdx.x / NSTAT;
  const int s   = blockIdx.x % NSTAT;
  const int tid = threadIdx.x;
  const size_t base = (size_t)b * T_ + (size_t)s * 1024;

  const float4 av = ((const float4*)(align + base))[tid];
  const int4   mv = ((const int4*)(mask + base))[tid];
  float sc[4];
  sc[0] = mv.x ? av.x : NEG_INF_F;
  sc[1] = mv.y ? av.y : NEG_INF_F;
  sc[2] = mv.z ? av.z : NEG_INF_F;
  sc[3] = mv.w ? av.w : NEG_INF_F;

  float lmax = fmaxf(fmaxf(sc[0], sc[1]), fmaxf(sc[2], sc[3]));
#pragma unroll
  for (int off = 32; off > 0; off >>= 1) lmax = fmaxf(lmax, __shfl_xor(lmax, off));

  __shared__ float red[4];
  __shared__ float s_m;
  if ((tid & 63) == 0) red[tid >> 6] = lmax;
  __syncthreads();
  if (tid == 0) s_m = fmaxf(fmaxf(red[0], red[1]), fmaxf(red[2], red[3]));
  __syncthreads();
  const float m = s_m;

  float lsum = __expf(sc[0] - m) + __expf(sc[1] - m) +
               __expf(sc[2] - m) + __expf(sc[3] - m);
#pragma unroll
  for (int off = 32; off > 0; off >>= 1) lsum += __shfl_xor(lsum, off);
  if ((tid & 63) == 0) red[tid >> 6] = lsum;
  __syncthreads();
  if (tid == 0) stats[blockIdx.x] = make_float2(m, red[0] + red[1] + red[2] + red[3]);
}

// ---------------------------------------------------------------------------
// Kernel 2: stream. Block (b, chunk): merge the 8 (m_i,l_i) pairs (64 B,
// L2-hit), compute the block's 512 weights inline from its own align/mask
// slice (4 KB, L3-hot), then stream the 128 KB value slab with nontemporal
// float4 loads. Deterministic partials to ws.
// ---------------------------------------------------------------------------
__global__ __launch_bounds__(256) void k_stream(const float* __restrict__ align,
                                                const int* __restrict__ mask,
                                                const float* __restrict__ value,
                                                const float2* __restrict__ stats,
                                                float* __restrict__ partial) {
  const int b     = blockIdx.x / NCHUNK;
  const int chunk = blockIdx.x % NCHUNK;
  const int tid   = threadIdx.x;

  // ---- merge partial stats (every thread, redundant, 64 B from L2) ----
  const f4* st = (const f4*)(stats + (size_t)b * NSTAT);  // 8 float2 = 4 f4
  const f4 s0 = st[0], s1 = st[1], s2 = st[2], s3 = st[3];
  float m = fmaxf(fmaxf(fmaxf(s0.x, s0.z), fmaxf(s1.x, s1.z)),
                  fmaxf(fmaxf(s2.x, s2.z), fmaxf(s3.x, s3.z)));
  float l = s0.y * __expf(s0.x - m) + s0.w * __expf(s0.z - m) +
            s1.y * __expf(s1.x - m) + s1.w * __expf(s1.z - m) +
            s2.y * __expf(s2.x - m) + s2.w * __expf(s2.z - m) +
            s3.y * __expf(s3.x - m) + s3.w * __expf(s3.z - m);
  const float invl = 1.0f / l;

  // ---- compute own 512 weights inline -> LDS ----
  const size_t sbase = (size_t)b * T_ + (size_t)chunk * CHUNK;
  const float2 av = ((const float2*)(align + sbase))[tid];
  const int2   mv = ((const int2*)(mask + sbase))[tid];
  __shared__ float w_s[CHUNK];
  const float w0 = __expf((mv.x ? av.x : NEG_INF_F) - m) * invl;
  const float w1 = __expf((mv.y ? av.y : NEG_INF_F) - m) * invl;
  ((float2*)w_s)[tid] = make_float2(w0, w1);
  __syncthreads();

  // ---- stream the 128 KB value slab (nontemporal, coalesced) ----
  const int grp  = tid >> 4;   // row within the 16-row slab
  const int lane = tid & 15;   // which float4 of the 64-float row
  const f4* v4 = (const f4*)(value + (size_t)b * T_ * U_) +
                 (size_t)chunk * CHUNK * 16;

  f4 acc = (f4)(0.f);
#pragma unroll 4
  for (int it = 0; it < CHUNK / 16; ++it) {
    const int tl = it * 16 + grp;
    const float wt = w_s[tl];
    const f4 v = __builtin_nontemporal_load(&v4[(size_t)tl * 16 + lane]);
    acc += wt * v;
  }

  // ---- block reduction over the 16 row-groups ----
  __shared__ f4 lds[16][16];
  lds[grp][lane] = acc;
  __syncthreads();
#pragma unroll
  for (int s = 8; s > 0; s >>= 1) {
    if (grp < s) {
      acc += lds[grp + s][lane];
      lds[grp][lane] = acc;
    }
    __syncthreads();
  }
  if (grp == 0) {
    f4* p = (f4*)(partial + ((size_t)b * NCHUNK + chunk) * U_);
    p[lane] = acc;
  }
}

// ---------------------------------------------------------------------------
// Kernel 3: reduce the NCHUNK partials per (b,u) -> out. 8192 outputs.
// ---------------------------------------------------------------------------
__global__ __launch_bounds__(256) void k_final(const float* __restrict__ partial,
                                               float* __restrict__ out) {
  const int idx = blockIdx.x * blockDim.x + threadIdx.x;  // 0 .. B*U-1
  const int b = idx / U_;
  const int u = idx % U_;
  const float* p = partial + (size_t)b * NCHUNK * U_ + u;
  float s = 0.f;
#pragma unroll
  for (int c = 0; c < NCHUNK; ++c) s += p[c * U_];
  out[idx] = s;
}

extern "C" void kernel_launch(void* const* d_in, const int* in_sizes, int n_in,
                              void* d_out, int out_size, void* d_ws, size_t ws_size,
                              hipStream_t stream) {
  const float* align = (const float*)d_in[0];
  const float* value = (const float*)d_in[1];
  const int*   mask  = (const int*)d_in[2];
  float* out = (float*)d_out;

  float2* stats   = (float2*)d_ws;                         // B*NSTAT float2 = 8 KiB
  float*  partial = (float*)d_ws + 2 * B_ * NSTAT;         // B*NCHUNK*U floats = 512 KiB

  k_stats<<<B_ * NSTAT, 256, 0, stream>>>(align, mask, stats);
  k_stream<<<B_ * NCHUNK, 256, 0, stream>>>(align, mask, value, stats, partial);
  k_final<<<(B_ * U_) / 256, 256, 0, stream>>>(partial, out);
}

// Round 5
// 50.476 us; speedup vs baseline: 1.1464x; 1.0608x over previous
//
#include <hip/hip_runtime.h>
#include <math.h>

// NEG_INF = -2^32+1 (rounds to -4294967296.0f in fp32, same as the reference's cast)
#define NEG_INF_F (-4294967295.0f)

typedef float f4 __attribute__((ext_vector_type(4)));

constexpr int B_ = 128;
constexpr int T_ = 8192;
constexpr int U_ = 64;
constexpr int NCHUNK = 16;           // blocks per batch
constexpr int CHUNK  = T_ / NCHUNK;  // 512 rows per block
constexpr int WROWS  = CHUNK / 4;    // 128 rows per wave
constexpr int NW     = NCHUNK * 4;   // 64 wave-partials per batch

// ---------------------------------------------------------------------------
// Single-pass flash-style kernel. Each wave owns 128 rows: computes local
// masked max m_w and local sum s_w = sum exp(x-m_w), then streams its 32 KB
// value slab (nontemporal) accumulating UNNORMALIZED p_w[u] = sum exp(x-m_w)*v.
// No inter-block (or even inter-wave) dependency -> value streaming starts
// ~immediately. Partials (m_w, s_w, p_w[64]) go to ws deterministically.
// ---------------------------------------------------------------------------
__global__ __launch_bounds__(256) void k_stream(const float* __restrict__ align,
                                                const int* __restrict__ mask,
                                                const float* __restrict__ value,
                                                float2* __restrict__ ms,
                                                float* __restrict__ p) {
  const int b     = blockIdx.x / NCHUNK;
  const int chunk = blockIdx.x % NCHUNK;
  const int tid   = threadIdx.x;
  const int wid   = tid >> 6;
  const int lane  = tid & 63;
  const int g     = lane >> 4;   // row-group within wave (4 rows per iter)
  const int s     = lane & 15;   // float4 slot within the 64-float row

  const int t0 = chunk * CHUNK + wid * WROWS;  // wave's first row

  // ---- wave-local masked scores: 2 per lane, coalesced 512B per wave ----
  const size_t abase = (size_t)b * T_ + t0;
  const float2 av = ((const float2*)(align + abase))[lane];
  const int2   mv = ((const int2*)(mask + abase))[lane];
  const float x0 = mv.x ? av.x : NEG_INF_F;
  const float x1 = mv.y ? av.y : NEG_INF_F;

  float m = fmaxf(x0, x1);
#pragma unroll
  for (int off = 32; off > 0; off >>= 1) m = fmaxf(m, __shfl_xor(m, off));

  const float e0 = __expf(x0 - m);
  const float e1 = __expf(x1 - m);
  float ssum = e0 + e1;
#pragma unroll
  for (int off = 32; off > 0; off >>= 1) ssum += __shfl_xor(ssum, off);

  // ---- stage wave's 128 unnormalized weights in its private LDS strip ----
  __shared__ float w_lds[4 * WROWS];
  ((float2*)(w_lds + wid * WROWS))[lane] = make_float2(e0, e1);
  __syncthreads();  // orders LDS (wave-private data; barrier is belt+braces)

  // ---- stream the wave's 32 KB value slab, nontemporal ----
  const f4* v4 = (const f4*)(value + (size_t)b * T_ * U_) + (size_t)t0 * 16;
  const float* wl = w_lds + wid * WROWS;

  f4 acc = (f4)(0.f);
#pragma unroll 8
  for (int it = 0; it < WROWS / 4; ++it) {
    const int r = it * 4 + g;
    const float wt = wl[r];                                   // broadcast read
    const f4 v = __builtin_nontemporal_load(&v4[(size_t)r * 16 + s]);
    acc += wt * v;
  }

  // ---- reduce the 4 row-groups inside the wave (shfl, no LDS) ----
#pragma unroll
  for (int off = 16; off <= 32; off <<= 1) {
    acc.x += __shfl_xor(acc.x, off);
    acc.y += __shfl_xor(acc.y, off);
    acc.z += __shfl_xor(acc.z, off);
    acc.w += __shfl_xor(acc.w, off);
  }

  const int wg = chunk * 4 + wid;  // wave-partial index within batch, 0..63
  if (g == 0) {
    f4* pp = (f4*)(p + ((size_t)b * NW + wg) * U_);
    pp[s] = acc;
  }
  if (lane == 0) ms[(size_t)b * NW + wg] = make_float2(m, ssum);
}

// ---------------------------------------------------------------------------
// Merge 64 wave-partials per batch with online-softmax rescale.
// 128 blocks x 64 threads (one wave per batch); thread u owns output u.
// ---------------------------------------------------------------------------
__global__ __launch_bounds__(64) void k_final(const float2* __restrict__ ms,
                                              const float* __restrict__ p,
                                              float* __restrict__ out) {
  const int b = blockIdx.x;
  const int u = threadIdx.x;

  const float2 msu = ms[(size_t)b * NW + u];  // thread j holds (m_j, s_j)
  float m = msu.x;
#pragma unroll
  for (int off = 32; off > 0; off >>= 1) m = fmaxf(m, __shfl_xor(m, off));

  const float e = __expf(msu.x - m);
  float d = msu.y * e;
#pragma unroll
  for (int off = 32; off > 0; off >>= 1) d += __shfl_xor(d, off);

  __shared__ float e_s[NW];
  e_s[u] = e;
  __syncthreads();

  const float* pb = p + (size_t)b * NW * U_ + u;
  float num = 0.f;
#pragma unroll
  for (int j = 0; j < NW; ++j) num += pb[(size_t)j * U_] * e_s[j];

  out[(size_t)b * U_ + u] = num / d;
}

extern "C" void kernel_launch(void* const* d_in, const int* in_sizes, int n_in,
                              void* d_out, int out_size, void* d_ws, size_t ws_size,
                              hipStream_t stream) {
  const float* align = (const float*)d_in[0];
  const float* value = (const float*)d_in[1];
  const int*   mask  = (const int*)d_in[2];
  float* out = (float*)d_out;

  float2* ms = (float2*)d_ws;                      // B*NW float2 = 64 KiB
  float*  p  = (float*)d_ws + 2 * (B_ * NW);       // B*NW*U floats = 2 MiB

  k_stream<<<B_ * NCHUNK, 256, 0, stream>>>(align, mask, value, ms, p);
  k_final<<<B_, 64, 0, stream>>>(ms, p, out);
}

// Round 6
// 49.139 us; speedup vs baseline: 1.1776x; 1.0272x over previous
//
#include <hip/hip_runtime.h>
#include <math.h>

// NEG_INF = -2^32+1 (rounds to -4294967296.0f in fp32, same as the reference's cast)
#define NEG_INF_F (-4294967295.0f)

typedef float f4 __attribute__((ext_vector_type(4)));

constexpr int B_ = 128;
constexpr int T_ = 8192;
constexpr int U_ = 64;
constexpr int NCHUNK = 16;           // blocks per batch
constexpr int CHUNK  = T_ / NCHUNK;  // 512 rows per block
constexpr int WROWS  = CHUNK / 4;    // 128 rows per wave

// ---------------------------------------------------------------------------
// Flash-style stream kernel. Each wave owns 128 rows: wave-local masked
// max/sum, unnormalized accumulate over its 32 KB value slab (2 independent
// load streams/lane), then a cross-wave online-softmax merge in LDS produces
// ONE block partial (m_blk, s_blk, p_blk[64]) -> 16 partials per batch.
// ---------------------------------------------------------------------------
__global__ __launch_bounds__(256) void k_stream(const float* __restrict__ align,
                                                const int* __restrict__ mask,
                                                const float* __restrict__ value,
                                                float2* __restrict__ ms,
                                                float* __restrict__ p) {
  const int b     = blockIdx.x / NCHUNK;
  const int chunk = blockIdx.x % NCHUNK;
  const int tid   = threadIdx.x;
  const int wid   = tid >> 6;
  const int lane  = tid & 63;
  const int g     = lane >> 4;   // row-group within wave
  const int s     = lane & 15;   // float4 slot within the 64-float row

  const int t0 = chunk * CHUNK + wid * WROWS;  // wave's first row

  // ---- wave-local masked scores: 2 per lane ----
  const size_t abase = (size_t)b * T_ + t0;
  const float2 av = ((const float2*)(align + abase))[lane];
  const int2   mv = ((const int2*)(mask + abase))[lane];
  const float x0 = mv.x ? av.x : NEG_INF_F;
  const float x1 = mv.y ? av.y : NEG_INF_F;

  float m = fmaxf(x0, x1);
#pragma unroll
  for (int off = 32; off > 0; off >>= 1) m = fmaxf(m, __shfl_xor(m, off));

  const float e0 = __expf(x0 - m);
  const float e1 = __expf(x1 - m);
  float ssum = e0 + e1;
#pragma unroll
  for (int off = 32; off > 0; off >>= 1) ssum += __shfl_xor(ssum, off);

  // ---- stage wave's 128 unnormalized weights in its private LDS strip ----
  __shared__ float w_lds[4 * WROWS];
  ((float2*)(w_lds + wid * WROWS))[lane] = make_float2(e0, e1);
  __syncthreads();

  // ---- stream the wave's 32 KB value slab: 2 rows/lane/iter, dual acc ----
  const f4* v4 = (const f4*)(value + (size_t)b * T_ * U_) + (size_t)t0 * 16;
  const float* wl = w_lds + wid * WROWS;

  f4 acc0 = (f4)(0.f), acc1 = (f4)(0.f);
#pragma unroll 4
  for (int it = 0; it < WROWS / 8; ++it) {
    const int r0 = it * 8 + g;
    const float wA = wl[r0];
    const float wB = wl[r0 + 4];
    const f4 vA = __builtin_nontemporal_load(&v4[(size_t)r0 * 16 + s]);
    const f4 vB = __builtin_nontemporal_load(&v4[(size_t)(r0 + 4) * 16 + s]);
    acc0 += wA * vA;
    acc1 += wB * vB;
  }
  f4 acc = acc0 + acc1;

  // ---- reduce the 4 row-groups inside the wave ----
#pragma unroll
  for (int off = 16; off <= 32; off <<= 1) {
    acc.x += __shfl_xor(acc.x, off);
    acc.y += __shfl_xor(acc.y, off);
    acc.z += __shfl_xor(acc.z, off);
    acc.w += __shfl_xor(acc.w, off);
  }

  // ---- cross-wave online-softmax merge -> one block partial ----
  __shared__ f4    s_acc[4][16];   // [wave][f4 slot]
  __shared__ float s_m[4], s_s[4];
  if (g == 0) s_acc[wid][s] = acc;
  if (lane == 0) { s_m[wid] = m; s_s[wid] = ssum; }
  __syncthreads();

  if (wid == 0) {
    const float m0 = s_m[0], m1 = s_m[1], m2 = s_m[2], m3 = s_m[3];
    const float mb = fmaxf(fmaxf(m0, m1), fmaxf(m2, m3));
    const float c0 = __expf(m0 - mb), c1 = __expf(m1 - mb);
    const float c2 = __expf(m2 - mb), c3 = __expf(m3 - mb);
    const float* sa = (const float*)s_acc;  // [4][64]
    const float pb = c0 * sa[lane] + c1 * sa[64 + lane] +
                     c2 * sa[128 + lane] + c3 * sa[192 + lane];
    p[((size_t)b * NCHUNK + chunk) * U_ + lane] = pb;
    if (lane == 0) {
      const float sb = c0 * s_s[0] + c1 * s_s[1] + c2 * s_s[2] + c3 * s_s[3];
      ms[(size_t)b * NCHUNK + chunk] = make_float2(mb, sb);
    }
  }
}

// ---------------------------------------------------------------------------
// Merge 16 block-partials per batch. 128 blocks x 64 threads; thread u owns
// output u. The 16 (m_j,s_j) pairs (128 B) broadcast from L1.
// ---------------------------------------------------------------------------
__global__ __launch_bounds__(64) void k_final(const float2* __restrict__ ms,
                                              const float* __restrict__ p,
                                              float* __restrict__ out) {
  const int b = blockIdx.x;
  const int u = threadIdx.x;

  const float2* msb = ms + (size_t)b * NCHUNK;
  float mj[NCHUNK], sj[NCHUNK];
  float m = NEG_INF_F;
#pragma unroll
  for (int j = 0; j < NCHUNK; ++j) {
    const float2 v = msb[j];
    mj[j] = v.x; sj[j] = v.y;
    m = fmaxf(m, v.x);
  }
  float d = 0.f;
  float ej[NCHUNK];
#pragma unroll
  for (int j = 0; j < NCHUNK; ++j) { ej[j] = __expf(mj[j] - m); d += sj[j] * ej[j]; }

  const float* pb = p + (size_t)b * NCHUNK * U_ + u;
  float num = 0.f;
#pragma unroll
  for (int j = 0; j < NCHUNK; ++j) num += pb[(size_t)j * U_] * ej[j];

  out[(size_t)b * U_ + u] = num / d;
}

extern "C" void kernel_launch(void* const* d_in, const int* in_sizes, int n_in,
                              void* d_out, int out_size, void* d_ws, size_t ws_size,
                              hipStream_t stream) {
  const float* align = (const float*)d_in[0];
  const float* value = (const float*)d_in[1];
  const int*   mask  = (const int*)d_in[2];
  float* out = (float*)d_out;

  float2* ms = (float2*)d_ws;                        // B*NCHUNK float2 = 16 KiB
  float*  p  = (float*)d_ws + 2 * (B_ * NCHUNK);     // B*NCHUNK*U floats = 512 KiB

  k_stream<<<B_ * NCHUNK, 256, 0, stream>>>(align, mask, value, ms, p);
  k_final<<<B_, 64, 0, stream>>>(ms, p, out);
}